// Round 5
// baseline (363.250 us; speedup 1.0000x reference)
//
#include <hip/hip_runtime.h>
#include <hip/hip_bf16.h>

// det(S) = |q_t|^2 |q_{t-1}|^2 is mathematically real-positive; the output is
// fp32 cancellation noise. numpy's einsum preserves the exact quaternion
// structure of S (S11 == conj(S00), S10 == -conj(S01) bitwise — mirror-pair
// products cancel identically for both fused and unfused complex multiply),
// so numpy's ONLY noise source is the det-product ufunc's FMA-fused complex
// multiply: im = fma(xr, yi, fl(xi*yr)), which with y = conj(x) equals the
// multiply rounding residue delta = fl(r*i) - r*i. We reproduce exactly that:
// plain (contract-off) arithmetic for S, explicit fmaf for the det products.
// det_im = fl(delta00 + delta01) — statistically identical to numpy's; the
// mean over 16.7M samples concentrates to ~0.3%.

#define GEO_NPAIR 524288   // 8192 * 64 quaternions per time slice
#define GEO_NT 33
#define GEO_NBLOCKS 2048   // GEO_NPAIR / 256

__global__ void GeodesicPathIntegrator_87462714016195_kernel(const float* trace,
                                                             double* partial) {
#pragma clang fp contract(off)
#pragma clang fp reassociate(off)
  const float4* q4 = (const float4*)trace;
  const int idx = blockIdx.x * 256 + threadIdx.x;   // flattened (b*64+k)

  float4 p = q4[idx];          // q_{t-1}; each element loaded exactly once
  double acc = 0.0;

  for (int t = 1; t < GEO_NT; ++t) {
    const float4 q = q4[t * GEO_NPAIR + idx];       // coalesced 16B/lane
    const float a1 = p.x, b1 = p.y, c1 = p.z, d1 = p.w;
    const float a2 = q.x, b2 = q.y, c2 = q.z, d2 = q.w;
    p = q;

    // S00 = (a2+i d2)(a1-i d1) + (b2+i c2)(b1-i c1)   [plain mul/sub/add]
    const float u0r = (a2 * a1) - (d2 * -d1);
    const float u0i = (a2 * -d1) + (d2 * a1);
    const float u1r = (b2 * b1) - (c2 * -c1);
    const float u1i = (b2 * -c1) + (c2 * b1);
    const float s00r = u0r + u1r;
    const float s00i = u0i + u1i;
    // S01 = (a2+i d2)(-b1-i c1) + (b2+i c2)(a1+i d1)
    const float v0r = (a2 * -b1) - (d2 * -c1);
    const float v0i = (a2 * -c1) + (d2 * -b1);
    const float v1r = (b2 * a1) - (c2 * d1);
    const float v1i = (b2 * d1) + (c2 * a1);
    const float s01r = v0r + v1r;
    const float s01i = v0i + v1i;
    // (S11, S10 are exactly (s00r,-s00i), (-s01r,s01i) — used inline below.)

    // det products, numpy-style fused complex multiply:
    //   re = fma(xr, yr, -(xi*yi)),  im = fma(xr, yi, +(xi*yr))
    // p0 = S00*S11, p1 = S01*S10; the im parts reduce to multiply residues.
    const float p0r = __builtin_fmaf(s00r, s00r, (s00i * s00i));
    const float p0i = __builtin_fmaf(s00r, -s00i, (s00i * s00r));   // = delta00
    const float p1r = __builtin_fmaf(s01r, -s01r, -(s01i * s01i));
    const float p1i = __builtin_fmaf(s01r, s01i, (s01i * -s01r));   // = -delta01
    const float detr = p0r - p1r;       // ~ |S00|^2 + |S01|^2 > 0
    const float deti = p0i - p1i;       // = fl(delta00 + delta01)

    // angle = atan2(im, re); for re>0 and |im/re| ~ 1e-8 the series term
    // z^3/3 is ~1e-17 relative, so fp32(atan2) == fp32(im/re) to <= 1 ulp.
    float ang;
    if (detr > 0.0f && fabsf(deti) < 1e-4f * detr) {
      ang = deti / detr;
    } else {
      ang = atan2f(deti, detr);   // degenerate path (not expected)
    }
    acc += (double)fabsf(ang / 3.14159274f);   // float32(pi)
  }

  __shared__ double red[256];
  red[threadIdx.x] = acc;
  __syncthreads();
  for (int s = 128; s > 0; s >>= 1) {
    if ((int)threadIdx.x < s) red[threadIdx.x] += red[threadIdx.x + s];
    __syncthreads();
  }
  if (threadIdx.x == 0) partial[blockIdx.x] = red[0];
}

__global__ void GeodesicPathIntegrator_87462714016195_final(const double* partial,
                                                            float* out) {
  double acc = 0.0;
  for (int i = threadIdx.x; i < GEO_NBLOCKS; i += 256) acc += partial[i];
  __shared__ double red[256];
  red[threadIdx.x] = acc;
  __syncthreads();
  for (int s = 128; s > 0; s >>= 1) {
    if ((int)threadIdx.x < s) red[threadIdx.x] += red[threadIdx.x + s];
    __syncthreads();
  }
  if (threadIdx.x == 0) {
    const double total = red[0] / (double)GEO_NPAIR;  // sum over t of per-t means
    out[0] = (float)(total / 32.0);                   // avg_curvature
    out[1] = (float)total;                            // total_eta
  }
}

extern "C" void kernel_launch(void* const* d_in, const int* in_sizes, int n_in,
                              void* d_out, int out_size, void* d_ws, size_t ws_size,
                              hipStream_t stream) {
  const float* trace = (const float*)d_in[0];   // fp32 (33, 8192, 256)
  double* partial = (double*)d_ws;              // 2048 doubles of scratch
  float* out = (float*)d_out;                   // [avg_curvature, total_eta]

  GeodesicPathIntegrator_87462714016195_kernel<<<GEO_NBLOCKS, 256, 0, stream>>>(trace, partial);
  GeodesicPathIntegrator_87462714016195_final<<<1, 256, 0, stream>>>(partial, out);
}